// Round 1
// baseline (522.763 us; speedup 1.0000x reference)
//
#include <hip/hip_runtime.h>

// Problem: prediction [M=16,K=16,N=16,B=2048,C=10] fp32, label [B] int.
// out = mean over all (m,k,n,b) of (argmax_c pred == label[b]).
// NSLICE = 16*16*16*2048 = 8388608 slices of C=10 contiguous floats (40 B).
// Memory-bound: 320 MiB read once -> ~53 us roofline at 6.3 TB/s.

#define NSLICE (16 * 16 * 16 * 2048)
#define BATCH 2048
#define NCLS 10

__global__ void eval_init(unsigned int* cnt) {
    if (threadIdx.x == 0 && blockIdx.x == 0) *cnt = 0u;
}

__device__ __forceinline__ int argmax10(const float* f) {
    float best = f[0];
    int bi = 0;
#pragma unroll
    for (int j = 1; j < NCLS; ++j) {
        if (f[j] > best) { best = f[j]; bi = j; }  // first-max wins, matches jnp/torch
    }
    return bi;
}

// Each thread handles a PAIR of slices: 2 slices * 10 floats = 20 floats = 80 B,
// always 16B-aligned (80*p % 16 == 0), so five float4 loads per thread.
__global__ __launch_bounds__(256) void eval_acc(const float4* __restrict__ pred4,
                                                const int* __restrict__ label,
                                                unsigned int* __restrict__ cnt) {
    const unsigned long long p =
        (unsigned long long)blockIdx.x * blockDim.x + threadIdx.x;  // pair index, exact grid

    const float4 v0 = pred4[5 * p + 0];
    const float4 v1 = pred4[5 * p + 1];
    const float4 v2 = pred4[5 * p + 2];
    const float4 v3 = pred4[5 * p + 3];
    const float4 v4 = pred4[5 * p + 4];

    float f[20];
    f[0] = v0.x;  f[1] = v0.y;  f[2] = v0.z;  f[3] = v0.w;
    f[4] = v1.x;  f[5] = v1.y;  f[6] = v1.z;  f[7] = v1.w;
    f[8] = v2.x;  f[9] = v2.y;  f[10] = v2.z; f[11] = v2.w;
    f[12] = v3.x; f[13] = v3.y; f[14] = v3.z; f[15] = v3.w;
    f[16] = v4.x; f[17] = v4.y; f[18] = v4.z; f[19] = v4.w;

    // slice indices 2p, 2p+1 ; b = slice % BATCH ; 2p even -> b1 = b0 + 1 (<= 2047)
    const int b0 = (int)((2ull * p) & (BATCH - 1));
    const int lab0 = label[b0];
    const int lab1 = label[b0 + 1];

    int local = (argmax10(f) == lab0) + (argmax10(f + NCLS) == lab1);

    // wave-64 reduction
#pragma unroll
    for (int off = 32; off > 0; off >>= 1) local += __shfl_down(local, off, 64);

    __shared__ int wsum[4];
    const int wave = threadIdx.x >> 6;
    const int lane = threadIdx.x & 63;
    if (lane == 0) wsum[wave] = local;
    __syncthreads();
    if (threadIdx.x == 0) {
        const int s = wsum[0] + wsum[1] + wsum[2] + wsum[3];
        atomicAdd(cnt, (unsigned int)s);
    }
}

__global__ void eval_fin(const unsigned int* __restrict__ cnt, float* __restrict__ out) {
    if (threadIdx.x == 0 && blockIdx.x == 0) {
        // count <= 8388608 is exactly representable in fp32; /2^23 is exact
        out[0] = (float)(*cnt) * (1.0f / (float)NSLICE);
    }
}

extern "C" void kernel_launch(void* const* d_in, const int* in_sizes, int n_in,
                              void* d_out, int out_size, void* d_ws, size_t ws_size,
                              hipStream_t stream) {
    const float4* pred4 = (const float4*)d_in[0];
    const int* label = (const int*)d_in[1];
    unsigned int* cnt = (unsigned int*)d_ws;
    float* out = (float*)d_out;

    eval_init<<<1, 1, 0, stream>>>(cnt);

    // NSLICE/2 = 4194304 pair-threads; 256 threads/block -> 16384 blocks, exact fit
    const int threads = 256;
    const int blocks = (NSLICE / 2) / threads;
    eval_acc<<<blocks, threads, 0, stream>>>(pred4, label, cnt);

    eval_fin<<<1, 1, 0, stream>>>(cnt, out);
}